// Round 1
// baseline (1482.472 us; speedup 1.0000x reference)
//
#include <hip/hip_runtime.h>

// ---------------------------------------------------------------------------
// NCEAverage forward, MI355X (gfx950)
//   out[b,k]   = < l2norm(memory[idx[b,k]] @ W^T + bias), l2norm(feat[b] @ W^T + bias) > / T
//   new_memory = memory with rows y <- 0.5*memory[y] + 0.5*feat   (last-wins on dup y)
// Outputs concatenated: d_out[0:65536] = out, d_out[65536:] = new_memory (81920x2048 f32)
// ---------------------------------------------------------------------------

#define B_SZ     64
#define KP1      1024
#define D_IN     2048
#define D_PROJ   512
#define N_MEM    81920
#define INV_T    (1.0f / 0.07f)

typedef __bf16 bf16x8 __attribute__((ext_vector_type(8)));
typedef float  f32x4  __attribute__((ext_vector_type(4)));

__device__ __forceinline__ unsigned short f2bf(float f) {
    unsigned int u = __float_as_uint(f);
    unsigned int r = (u + 0x7FFFu + ((u >> 16) & 1u)) >> 16;   // RTN-even
    return (unsigned short)r;
}

// --- kernel 0: W fp32 -> bf16 (1M elems) -----------------------------------
__global__ void cvt_w_kernel(const float* __restrict__ W, unsigned short* __restrict__ Wb) {
    int i = blockIdx.x * 256 + threadIdx.x;          // x4 floats
    float4 v = ((const float4*)W)[i];
    ushort4 o;
    o.x = f2bf(v.x); o.y = f2bf(v.y); o.z = f2bf(v.z); o.w = f2bf(v.w);
    ((ushort4*)Wb)[i] = o;
}

// --- kernel 1: feat_proj = l2norm(feat @ W^T + bias), fp32 -----------------
// grid 64 (one block per batch row), block 256
__global__ void feat_proj_kernel(const float* __restrict__ feat,
                                 const float* __restrict__ W,
                                 const float* __restrict__ bias,
                                 float* __restrict__ fp_out) {
    const int b = blockIdx.x, tid = threadIdx.x;
    __shared__ float sF[D_IN];
    __shared__ float sP[D_PROJ];
    __shared__ float sRed[256];

    #pragma unroll
    for (int i = 0; i < D_IN / 256; ++i)
        sF[tid + i * 256] = feat[(long)b * D_IN + tid + i * 256];
    __syncthreads();

    float pv[2];
    #pragma unroll
    for (int pass = 0; pass < 2; ++pass) {
        const int n = tid + pass * 256;
        const float4* wr = (const float4*)(W + (long)n * D_IN);
        const float4* fr = (const float4*)sF;
        float s = 0.f;
        for (int j = 0; j < D_IN / 4; ++j) {
            float4 wv = wr[j], fv = fr[j];
            s += wv.x * fv.x + wv.y * fv.y + wv.z * fv.z + wv.w * fv.w;
        }
        pv[pass] = s + bias[n];
        sP[n] = pv[pass];
    }
    __syncthreads();
    sRed[tid] = pv[0] * pv[0] + pv[1] * pv[1];
    __syncthreads();
    for (int s = 128; s > 0; s >>= 1) {
        if (tid < s) sRed[tid] += sRed[tid + s];
        __syncthreads();
    }
    const float rn = rsqrtf(sRed[0]);
    fp_out[(long)b * D_PROJ + tid]       = pv[0] * rn;
    fp_out[(long)b * D_PROJ + tid + 256] = pv[1] * rn;
}

// --- kernel 2: fused gather-GEMM-norm-dot ----------------------------------
// grid 1024, block 256 (4 waves). Block handles 64 gathered rows x all 512 cols.
// Wave w covers cols [w*128, w*128+128). MFMA 16x16x32 bf16.
#define AS_STRIDE 72   // 64 + 8 pad: row stride 144 B breaks 16-way bank conflict
__global__ __launch_bounds__(256, 2)
void main_gemm_kernel(const float* __restrict__ memory,
                      const int* __restrict__ idx,
                      const unsigned short* __restrict__ Wb,
                      const float* __restrict__ fp,
                      const float* __restrict__ bias,
                      float* __restrict__ out) {
    const int tid  = threadIdx.x;
    const int w    = tid >> 6;
    const int lane = tid & 63;
    const int quad = lane >> 4;
    const int c16  = lane & 15;
    const int blk  = blockIdx.x;
    const int b    = blk >> 4;             // (blk*64)/1024

    __shared__ unsigned short As[64 * AS_STRIDE];
    __shared__ float sFP[D_PROJ];
    __shared__ float sBias[D_PROJ];
    __shared__ int   sIdx[64];
    __shared__ float sSS[4 * 64];
    __shared__ float sDot[4 * 64];

    for (int i = tid; i < D_PROJ; i += 256) {
        sFP[i]   = fp[(long)b * D_PROJ + i];
        sBias[i] = bias[i];
    }
    if (tid < 64) sIdx[tid] = idx[blk * 64 + tid];
    __syncthreads();

    f32x4 acc[4][8];
    const f32x4 zero = {0.f, 0.f, 0.f, 0.f};
    #pragma unroll
    for (int mt = 0; mt < 4; ++mt)
        #pragma unroll
        for (int nt = 0; nt < 8; ++nt) acc[mt][nt] = zero;

    const int  row  = tid >> 2;            // 0..63
    const int  q    = tid & 3;             // 16-float quarter of a 64-k slab
    const long arow = (long)sIdx[row] * D_IN;

    for (int k0 = 0; k0 < D_IN; k0 += 64) {
        // issue global loads early (before barrier)
        const float4* src = (const float4*)(memory + arow + k0 + q * 16);
        float4 v0 = src[0], v1 = src[1], v2 = src[2], v3 = src[3];

        __syncthreads();   // prev tile's compute done
        float f[16] = {v0.x, v0.y, v0.z, v0.w, v1.x, v1.y, v1.z, v1.w,
                       v2.x, v2.y, v2.z, v2.w, v3.x, v3.y, v3.z, v3.w};
        unsigned int pk[8];
        #pragma unroll
        for (int j = 0; j < 8; ++j)
            pk[j] = (unsigned int)f2bf(f[2 * j]) | ((unsigned int)f2bf(f[2 * j + 1]) << 16);
        uint4* dst = (uint4*)&As[row * AS_STRIDE + q * 16];
        dst[0] = make_uint4(pk[0], pk[1], pk[2], pk[3]);
        dst[1] = make_uint4(pk[4], pk[5], pk[6], pk[7]);
        __syncthreads();   // As ready

        #pragma unroll
        for (int ks = 0; ks < 2; ++ks) {
            bf16x8 af[4];
            #pragma unroll
            for (int mt = 0; mt < 4; ++mt)
                af[mt] = *(const bf16x8*)&As[(mt * 16 + c16) * AS_STRIDE + ks * 32 + quad * 8];
            #pragma unroll
            for (int nt = 0; nt < 8; ++nt) {
                const int n = w * 128 + nt * 16 + c16;
                bf16x8 bfr = *(const bf16x8*)&Wb[(long)n * D_IN + k0 + ks * 32 + quad * 8];
                #pragma unroll
                for (int mt = 0; mt < 4; ++mt)
                    acc[mt][nt] = __builtin_amdgcn_mfma_f32_16x16x32_bf16(
                        af[mt], bfr, acc[mt][nt], 0, 0, 0);
            }
        }
    }

    // Epilogue: per-row sum(P^2) and sum(P*fp).  D layout: row=quad*4+r, col=c16.
    float ssl[4][4], dtl[4][4];
    #pragma unroll
    for (int mt = 0; mt < 4; ++mt)
        #pragma unroll
        for (int r = 0; r < 4; ++r) { ssl[mt][r] = 0.f; dtl[mt][r] = 0.f; }

    #pragma unroll
    for (int nt = 0; nt < 8; ++nt) {
        const int n = w * 128 + nt * 16 + c16;
        const float bv = sBias[n], fv = sFP[n];
        #pragma unroll
        for (int mt = 0; mt < 4; ++mt)
            #pragma unroll
            for (int r = 0; r < 4; ++r) {
                const float P = acc[mt][nt][r] + bv;
                ssl[mt][r] += P * P;
                dtl[mt][r] += P * fv;
            }
    }
    #pragma unroll
    for (int off = 8; off >= 1; off >>= 1)
        #pragma unroll
        for (int mt = 0; mt < 4; ++mt)
            #pragma unroll
            for (int r = 0; r < 4; ++r) {
                ssl[mt][r] += __shfl_xor(ssl[mt][r], off);
                dtl[mt][r] += __shfl_xor(dtl[mt][r], off);
            }
    if (c16 == 0) {
        #pragma unroll
        for (int mt = 0; mt < 4; ++mt)
            #pragma unroll
            for (int r = 0; r < 4; ++r) {
                const int rr = mt * 16 + quad * 4 + r;
                sSS[w * 64 + rr]  = ssl[mt][r];
                sDot[w * 64 + rr] = dtl[mt][r];
            }
    }
    __syncthreads();
    if (tid < 64) {
        const float ss = sSS[tid] + sSS[64 + tid] + sSS[128 + tid] + sSS[192 + tid];
        const float dt = sDot[tid] + sDot[64 + tid] + sDot[128 + tid] + sDot[192 + tid];
        out[blk * 64 + tid] = dt * rsqrtf(ss) * INV_T;
    }
}

// --- kernel 3: copy memory -> out_mem (grid-stride float4) -----------------
__global__ void copy_mem_kernel(const float4* __restrict__ src,
                                float4* __restrict__ dst, long n4) {
    long i = (long)blockIdx.x * blockDim.x + threadIdx.x;
    const long stride = (long)gridDim.x * blockDim.x;
    for (; i < n4; i += stride) dst[i] = src[i];
}

// --- kernel 4: momentum scatter update (last-wins) -------------------------
__global__ void scatter_kernel(const float* __restrict__ memory,
                               const float* __restrict__ feat,
                               const int* __restrict__ y,
                               float* __restrict__ out_mem) {
    const int i  = blockIdx.x;             // 0..63
    const int yi = y[i];
    for (int j = i + 1; j < B_SZ; ++j)
        if (y[j] == yi) return;            // a later write wins
    const float4* m4 = (const float4*)(memory + (long)yi * D_IN);
    const float4* f4 = (const float4*)(feat + (long)i * D_IN);
    float4* o4 = (float4*)(out_mem + (long)yi * D_IN);
    for (int c = threadIdx.x; c < D_IN / 4; c += 256) {
        float4 a = m4[c], b = f4[c];
        float4 r;
        r.x = 0.5f * (a.x + b.x); r.y = 0.5f * (a.y + b.y);
        r.z = 0.5f * (a.z + b.z); r.w = 0.5f * (a.w + b.w);
        o4[c] = r;
    }
}

extern "C" void kernel_launch(void* const* d_in, const int* in_sizes, int n_in,
                              void* d_out, int out_size, void* d_ws, size_t ws_size,
                              hipStream_t stream) {
    const float* feat   = (const float*)d_in[0];
    const int*   y      = (const int*)d_in[1];
    const int*   idx    = (const int*)d_in[2];
    const float* memory = (const float*)d_in[3];
    const float* W      = (const float*)d_in[4];
    const float* bias   = (const float*)d_in[5];

    float* out     = (float*)d_out;                 // [65536]
    float* out_mem = out + (long)B_SZ * KP1;        // [81920*2048]

    // Scratch lives in the out_mem region (671 MB) and is overwritten by the
    // copy kernel afterwards -> no dependence on ws_size.
    unsigned short* Wb = (unsigned short*)out_mem;                 // 2 MB
    float*          fp = out_mem + (long)D_PROJ * D_IN;            // 128 KB, after Wb

    cvt_w_kernel<<<(D_PROJ * D_IN) / (4 * 256), 256, 0, stream>>>(W, Wb);
    feat_proj_kernel<<<B_SZ, 256, 0, stream>>>(feat, W, bias, fp);
    main_gemm_kernel<<<(B_SZ * KP1) / 64, 256, 0, stream>>>(memory, idx, Wb, fp, bias, out);

    const long n4 = (long)N_MEM * D_IN / 4;
    copy_mem_kernel<<<32768, 256, 0, stream>>>((const float4*)memory, (float4*)out_mem, n4);
    scatter_kernel<<<B_SZ, 256, 0, stream>>>(memory, feat, y, out_mem);
}